// Round 1
// baseline (81.485 us; speedup 1.0000x reference)
//
#include <hip/hip_runtime.h>
#include <hip/hip_bf16.h>
#include <math.h>

#define BGR 128   // graphs
#define NND 512   // nodes per graph
#define DFD 128   // feature dim
#define KKP 256   // kept nodes per graph

// ---------------- kernel 1: support[b][n] = dot(X[b][n], w) ----------------
__global__ __launch_bounds__(256) void k_support(const float* __restrict__ X,
                                                 const float* __restrict__ W,
                                                 float* __restrict__ sup) {
    __shared__ float w_s[DFD];
    int t = threadIdx.x;
    if (t < DFD) w_s[t] = W[t];
    __syncthreads();
    int node = blockIdx.x * 64 + (t >> 2);   // global node in [0, B*N)
    int q = t & 3;                            // quarter of the D=128 row
    const float4* xp = (const float4*)(X + (size_t)node * DFD + q * 32);
    const float4* wp = (const float4*)(w_s + q * 32);
    float sum = 0.f;
#pragma unroll
    for (int i = 0; i < 8; ++i) {
        float4 x = xp[i], w = wp[i];
        sum += x.x * w.x + x.y * w.y + x.z * w.z + x.w * w.w;
    }
    sum += __shfl_xor(sum, 1);
    sum += __shfl_xor(sum, 2);
    if (q == 0) sup[node] = sum;
}

// ------------- kernel 2: attn[b][n] = tanh(dot(A[b][n][:], sup[b]) + bias) -------------
__global__ __launch_bounds__(256) void k_score(const float* __restrict__ A,
                                               const float* __restrict__ sup,
                                               const float* __restrict__ bias,
                                               float* __restrict__ attn) {
    __shared__ float sup_s[NND];
    int b = blockIdx.x >> 6;       // 64 blocks per graph, 8 rows per block
    int rblk = blockIdx.x & 63;
    int t = threadIdx.x;
    sup_s[t] = sup[b * NND + t];
    sup_s[256 + t] = sup[b * NND + 256 + t];
    __syncthreads();
    int wave = t >> 6, l = t & 63;
    float bias0 = bias[0];
    const float4* sp = (const float4*)sup_s;
    float4 s0 = sp[l], s1 = sp[64 + l];
#pragma unroll
    for (int r = 0; r < 2; ++r) {
        int row = rblk * 8 + wave * 2 + r;
        const float4* ap = (const float4*)(A + ((size_t)b * NND + row) * NND);
        float4 a0 = ap[l], a1 = ap[64 + l];
        float sum = a0.x * s0.x + a0.y * s0.y + a0.z * s0.z + a0.w * s0.w
                  + a1.x * s1.x + a1.y * s1.y + a1.z * s1.z + a1.w * s1.w;
#pragma unroll
        for (int off = 32; off >= 1; off >>= 1) sum += __shfl_down(sum, off);
        if (l == 0) attn[b * NND + row] = tanhf(sum + bias0);
    }
}

// ------- kernel 3: per-graph top-K (rank-based, tie-break by index), hidden, indicator -------
__global__ __launch_bounds__(256) void k_topk(const float* __restrict__ X,
                                              const float* __restrict__ attn,
                                              float* __restrict__ out_hidden,
                                              float* __restrict__ out_gi,
                                              int* __restrict__ gidx) {
    __shared__ float attn_s[NND];
    __shared__ unsigned int km[16];      // keep bitmask, 512 bits
    __shared__ int idx_s[KKP];
    int b = blockIdx.x, t = threadIdx.x;
    attn_s[t] = attn[b * NND + t];
    attn_s[256 + t] = attn[b * NND + 256 + t];
    __syncthreads();
    int wave = t >> 6, l = t & 63;

    float a0 = attn_s[t], a1 = attn_s[t + 256];
    int r0 = 0, r1 = 0;
    for (int j = 0; j < NND; ++j) {
        float v = attn_s[j];
        r0 += (v > a0 || (v == a0 && j < t)) ? 1 : 0;
        r1 += (v > a1 || (v == a1 && j < t + 256)) ? 1 : 0;
    }
    bool keep0 = r0 < KKP, keep1 = r1 < KKP;

    unsigned long long m0 = __ballot(keep0);
    unsigned long long m1 = __ballot(keep1);
    if (l == 0) {
        km[wave * 2]     = (unsigned int)m0;
        km[wave * 2 + 1] = (unsigned int)(m0 >> 32);
        km[8 + wave * 2]     = (unsigned int)m1;
        km[8 + wave * 2 + 1] = (unsigned int)(m1 >> 32);
    }
    __syncthreads();

#pragma unroll
    for (int h = 0; h < 2; ++h) {
        int i = t + 256 * h;
        bool kp = h == 0 ? keep0 : keep1;
        if (kp) {
            int w = i >> 5;
            int pos = 0;
            for (int u = 0; u < w; ++u) pos += __popc(km[u]);
            pos += __popc(km[w] & ((1u << (i & 31)) - 1u));
            idx_s[pos] = i;
            gidx[b * KKP + pos] = i;
        }
    }
    out_gi[b * KKP + t] = (float)b;
    __syncthreads();

    // hidden: each wave writes 64 contiguous kept rows
    for (int r = 0; r < 64; ++r) {
        int k = wave * 64 + r;
        int node = idx_s[k];
        float s = attn_s[node];
        const float2* xp = (const float2*)(X + ((size_t)b * NND + node) * DFD);
        float2 v = xp[l];
        v.x *= s; v.y *= s;
        ((float2*)(out_hidden + ((size_t)b * KKP + k) * DFD))[l] = v;
    }
}

// ------- kernel 4a: binarized gathered sub-adjacency as bitmask + dinv -------
__global__ __launch_bounds__(256) void k_bits(const float* __restrict__ A,
                                              const int* __restrict__ gidx,
                                              unsigned int* __restrict__ bits,
                                              float* __restrict__ dinv) {
    __shared__ int idx_s[KKP];
    __shared__ float rowbuf[4][NND];
    int b = blockIdx.x >> 3, blk = blockIdx.x & 7;   // 8 blocks/graph, 32 rows each
    int t = threadIdx.x, wave = t >> 6, l = t & 63;
    idx_s[t] = gidx[b * KKP + t];
    __syncthreads();
    for (int r = 0; r < 8; ++r) {
        int i = blk * 32 + wave * 8 + r;             // kept-row index in [0,K)
        int node = idx_s[i];
        const float4* ap = (const float4*)(A + ((size_t)b * NND + node) * NND);
        float4 v0 = ap[l], v1 = ap[64 + l];
        ((float4*)(rowbuf[wave]))[l] = v0;
        ((float4*)(rowbuf[wave]))[64 + l] = v1;
        __syncthreads();
        int rowsum = 1;                               // + I_K diagonal
        unsigned long long masks[4];
#pragma unroll
        for (int c = 0; c < 4; ++c) {
            int j = c * 64 + l;
            // reference masks the N x N diagonal BEFORE gathering -> force sub[i][i]=0
            bool bit = (j != i) && (rowbuf[wave][idx_s[j]] != 0.0f);
            masks[c] = __ballot(bit);
            rowsum += __popcll(masks[c]);
        }
        if (l == 0) {
            size_t base = ((size_t)b * KKP + i) * 8;
#pragma unroll
            for (int c = 0; c < 4; ++c) {
                bits[base + 2 * c]     = (unsigned int)masks[c];
                bits[base + 2 * c + 1] = (unsigned int)(masks[c] >> 32);
            }
            dinv[b * KKP + i] = 1.0f / sqrtf((float)rowsum);
        }
        __syncthreads();
    }
}

// ------- kernel 4b: mask_adjacency[i][j] = (bit + diag) * dinv_i * dinv_j -------
__global__ __launch_bounds__(256) void k_norm(const unsigned int* __restrict__ bits,
                                              const float* __restrict__ dinv,
                                              float* __restrict__ out_adj) {
    __shared__ float dinv_s[KKP];
    int b = blockIdx.x >> 5;       // 32 blocks/graph, 8 rows each
    int rblk = blockIdx.x & 31;
    int t = threadIdx.x, wave = t >> 6, l = t & 63;
    dinv_s[t] = dinv[b * KKP + t];
    __syncthreads();
    float4 dj = ((const float4*)dinv_s)[l];          // dinv for cols 4l..4l+3
    const float* djp = &dj.x;
#pragma unroll
    for (int r = 0; r < 2; ++r) {
        int i = rblk * 8 + wave * 2 + r;
        float di = dinv_s[i];
        const unsigned int* bp = bits + ((size_t)b * KKP + i) * 8;
        unsigned int word = bp[l >> 3];
        int j0 = l * 4;
        float4 v;
        float* pv = &v.x;
#pragma unroll
        for (int c = 0; c < 4; ++c) {
            int j = j0 + c;
            float ah = ((word >> (j & 31)) & 1u) ? 1.0f : 0.0f;
            if (j == i) ah += 1.0f;                  // + I_K
            pv[c] = ah * di * djp[c];
        }
        ((float4*)(out_adj + ((size_t)b * KKP + i) * KKP))[l] = v;
    }
}

extern "C" void kernel_launch(void* const* d_in, const int* in_sizes, int n_in,
                              void* d_out, int out_size, void* d_ws, size_t ws_size,
                              hipStream_t stream) {
    const float* A    = (const float*)d_in[0];   // [B,N,N]
    const float* X    = (const float*)d_in[1];   // [B,N,D]
    const float* W    = (const float*)d_in[3];   // [D,1]
    const float* bias = (const float*)d_in[4];   // [1]

    float* out        = (float*)d_out;
    float* out_hidden = out;                                     // B*K*D
    float* out_gi     = out + (size_t)BGR * KKP * DFD;           // B*K (as float)
    float* out_adj    = out_gi + (size_t)BGR * KKP;              // B*K*K

    float* sup  = (float*)d_ws;                                  // B*N
    float* attn = sup + (size_t)BGR * NND;                       // B*N
    int*   gidx = (int*)(attn + (size_t)BGR * NND);              // B*K
    float* dinv = (float*)(gidx + (size_t)BGR * KKP);            // B*K
    unsigned int* bits = (unsigned int*)(dinv + (size_t)BGR * KKP); // B*K*8

    k_support<<<BGR * NND / 64, 256, 0, stream>>>(X, W, sup);
    k_score<<<BGR * 64, 256, 0, stream>>>(A, sup, bias, attn);
    k_topk<<<BGR, 256, 0, stream>>>(X, attn, out_hidden, out_gi, gidx);
    k_bits<<<BGR * 8, 256, 0, stream>>>(A, gidx, bits, dinv);
    k_norm<<<BGR * 32, 256, 0, stream>>>(bits, dinv, out_adj);
}

// Round 2
// 71.005 us; speedup vs baseline: 1.1476x; 1.1476x over previous
//
#include <hip/hip_runtime.h>
#include <hip/hip_bf16.h>
#include <math.h>

#define BGR 128   // graphs
#define NND 512   // nodes per graph
#define DFD 128   // feature dim
#define KKP 256   // kept nodes per graph

typedef unsigned int uint;
typedef unsigned long long ull;

// ---------------- kernel 1: support[b][n] = dot(X[b][n], w) ----------------
__global__ __launch_bounds__(256) void k_support(const float* __restrict__ X,
                                                 const float* __restrict__ W,
                                                 float* __restrict__ sup) {
    __shared__ float w_s[DFD];
    int t = threadIdx.x;
    if (t < DFD) w_s[t] = W[t];
    __syncthreads();
    int node = blockIdx.x * 64 + (t >> 2);   // global node in [0, B*N)
    int q = t & 3;                            // quarter of the D=128 row
    const float4* xp = (const float4*)(X + (size_t)node * DFD + q * 32);
    const float4* wp = (const float4*)(w_s + q * 32);
    float sum = 0.f;
#pragma unroll
    for (int i = 0; i < 8; ++i) {
        float4 x = xp[i], w = wp[i];
        sum += x.x * w.x + x.y * w.y + x.z * w.z + x.w * w.w;
    }
    sum += __shfl_xor(sum, 1);
    sum += __shfl_xor(sum, 2);
    if (q == 0) sup[node] = sum;
}

// --- kernel 2: attn = tanh(A·sup + b); ALSO emit packed binarized bitmask of A ---
// bm layout per row: 8 ulls indexed k = h*4+c (h = col>>8, c = col&3);
// bit position within ull = (col>>2)&63.
__global__ __launch_bounds__(256) void k_score(const float* __restrict__ A,
                                               const float* __restrict__ sup,
                                               const float* __restrict__ bias,
                                               float* __restrict__ attn,
                                               ull* __restrict__ bm) {
    __shared__ float sup_s[NND];
    int b = blockIdx.x >> 6;       // 64 blocks per graph, 8 rows per block
    int rblk = blockIdx.x & 63;
    int t = threadIdx.x;
    sup_s[t] = sup[b * NND + t];
    sup_s[256 + t] = sup[b * NND + 256 + t];
    __syncthreads();
    int wave = t >> 6, l = t & 63;
    float bias0 = bias[0];
    const float4* sp = (const float4*)sup_s;
    float4 s0 = sp[l], s1 = sp[64 + l];
#pragma unroll
    for (int r = 0; r < 2; ++r) {
        int row = rblk * 8 + wave * 2 + r;
        const float4* ap = (const float4*)(A + ((size_t)b * NND + row) * NND);
        float4 a0 = ap[l], a1 = ap[64 + l];
        float sum = a0.x * s0.x + a0.y * s0.y + a0.z * s0.z + a0.w * s0.w
                  + a1.x * s1.x + a1.y * s1.y + a1.z * s1.z + a1.w * s1.w;
        int c0 = 4 * l;
        ull m[8];
        m[0] = __ballot(a0.x != 0.f && (c0 + 0) != row);
        m[1] = __ballot(a0.y != 0.f && (c0 + 1) != row);
        m[2] = __ballot(a0.z != 0.f && (c0 + 2) != row);
        m[3] = __ballot(a0.w != 0.f && (c0 + 3) != row);
        m[4] = __ballot(a1.x != 0.f && (256 + c0 + 0) != row);
        m[5] = __ballot(a1.y != 0.f && (256 + c0 + 1) != row);
        m[6] = __ballot(a1.z != 0.f && (256 + c0 + 2) != row);
        m[7] = __ballot(a1.w != 0.f && (256 + c0 + 3) != row);
#pragma unroll
        for (int off = 32; off >= 1; off >>= 1) sum += __shfl_down(sum, off);
        if (l == 0) {
            attn[b * NND + row] = tanhf(sum + bias0);
            ull* bp = bm + ((size_t)b * NND + row) * 8;
#pragma unroll
            for (int k = 0; k < 8; ++k) bp[k] = m[k];
        }
    }
}

// --- kernel 3 (fused): top-K ranks -> idx, hidden, indicator, K x K bits + dinv ---
__global__ __launch_bounds__(512) void k_fuse(const float* __restrict__ X,
                                              const float* __restrict__ attn,
                                              const uint* __restrict__ bm,
                                              float* __restrict__ out_hidden,
                                              float* __restrict__ out_gi,
                                              uint* __restrict__ bits,
                                              float* __restrict__ dinv) {
    __shared__ float attn_s[NND];
    __shared__ uint km[16];              // keep bitmask over 512 nodes
    __shared__ int idx_s[KKP];
    __shared__ uint4 bm_s4[KKP][4];      // gathered bitmask rows (16 uints each)
    __shared__ uint bits_s[KKP][8];      // K x K packed bits, K-order
    int b = blockIdx.x, t = threadIdx.x;
    attn_s[t] = attn[b * NND + t];
    __syncthreads();
    int wave = t >> 6, l = t & 63;

    // rank of node t (strictly-greater, ties broken by smaller index)
    float a = attn_s[t];
    int r = 0;
    const float4* ap4 = (const float4*)attn_s;
    for (int jj = 0; jj < 128; ++jj) {
        float4 v = ap4[jj];
        int j0 = jj * 4;
        r += (v.x > a || (v.x == a && j0     < t)) ? 1 : 0;
        r += (v.y > a || (v.y == a && j0 + 1 < t)) ? 1 : 0;
        r += (v.z > a || (v.z == a && j0 + 2 < t)) ? 1 : 0;
        r += (v.w > a || (v.w == a && j0 + 3 < t)) ? 1 : 0;
    }
    bool keep = r < KKP;
    ull mk = __ballot(keep);
    if (l == 0) { km[wave * 2] = (uint)mk; km[wave * 2 + 1] = (uint)(mk >> 32); }
    __syncthreads();
    if (keep) {
        int w = t >> 5, pos = 0;
        for (int u = 0; u < w; ++u) pos += __popc(km[u]);
        pos += __popc(km[w] & ((1u << (t & 31)) - 1u));
        idx_s[pos] = t;
    }
    if (t < KKP) out_gi[b * KKP + t] = (float)b;
    __syncthreads();

    // gather bitmask rows of kept nodes into LDS (64B per row, L2-hot)
    {
        int i = t >> 1, half = t & 1;
        const uint4* src = (const uint4*)(bm + ((size_t)b * NND + idx_s[i]) * 16) + half * 2;
        bm_s4[i][half * 2]     = src[0];
        bm_s4[i][half * 2 + 1] = src[1];
    }
    __syncthreads();

    // assemble K x K bits: thread t handles kept-col j = t&255, rows ii+rowoff
    const uint* bmw = (const uint*)bm_s4;
    int j = t & 255;
    int jn = idx_s[j];
    int widx = ((jn >> 8) * 4 + (jn & 3)) * 2 + ((jn >> 7) & 1);
    int bitpos = (jn >> 2) & 31;
    int rowoff = t >> 8;          // 0 or 1 (which half-block)
    int wq = (t >> 6) & 3;        // quarter of j-range this wave covers
    for (int ii = 0; ii < KKP; ii += 2) {
        int row = ii + rowoff;
        uint kb = (bmw[row * 16 + widx] >> bitpos) & 1u;
        ull mb = __ballot(kb != 0u);
        if (l == 0) {
            bits_s[row][wq * 2]     = (uint)mb;
            bits_s[row][wq * 2 + 1] = (uint)(mb >> 32);
            uint* gp = bits + ((size_t)b * KKP + row) * 8 + wq * 2;
            gp[0] = (uint)mb;
            gp[1] = (uint)(mb >> 32);
        }
    }
    __syncthreads();
    if (t < KKP) {
        int s = 1;   // + I_K diagonal
#pragma unroll
        for (int k = 0; k < 8; ++k) s += __popc(bits_s[t][k]);
        dinv[b * KKP + t] = 1.0f / sqrtf((float)s);
    }

    // hidden: 8 waves x 32 kept rows each
    for (int r2 = 0; r2 < 32; ++r2) {
        int k = wave * 32 + r2;
        int node = idx_s[k];
        float s = attn_s[node];
        const float2* xp = (const float2*)(X + ((size_t)b * NND + node) * DFD);
        float2 v = xp[l];
        v.x *= s; v.y *= s;
        ((float2*)(out_hidden + ((size_t)b * KKP + k) * DFD))[l] = v;
    }
}

// ------- kernel 4: mask_adjacency[i][j] = (bit + diag) * dinv_i * dinv_j -------
__global__ __launch_bounds__(256) void k_norm(const uint* __restrict__ bits,
                                              const float* __restrict__ dinv,
                                              float* __restrict__ out_adj) {
    __shared__ float dinv_s[KKP];
    int b = blockIdx.x >> 5;       // 32 blocks/graph, 8 rows each
    int rblk = blockIdx.x & 31;
    int t = threadIdx.x, wave = t >> 6, l = t & 63;
    dinv_s[t] = dinv[b * KKP + t];
    __syncthreads();
    float4 dj = ((const float4*)dinv_s)[l];          // dinv for cols 4l..4l+3
    const float* djp = &dj.x;
#pragma unroll
    for (int r = 0; r < 2; ++r) {
        int i = rblk * 8 + wave * 2 + r;
        float di = dinv_s[i];
        const uint* bp = bits + ((size_t)b * KKP + i) * 8;
        uint word = bp[l >> 3];
        int j0 = l * 4;
        float4 v;
        float* pv = &v.x;
#pragma unroll
        for (int c = 0; c < 4; ++c) {
            int j = j0 + c;
            float ah = ((word >> (j & 31)) & 1u) ? 1.0f : 0.0f;
            if (j == i) ah += 1.0f;                  // + I_K
            pv[c] = ah * di * djp[c];
        }
        ((float4*)(out_adj + ((size_t)b * KKP + i) * KKP))[l] = v;
    }
}

extern "C" void kernel_launch(void* const* d_in, const int* in_sizes, int n_in,
                              void* d_out, int out_size, void* d_ws, size_t ws_size,
                              hipStream_t stream) {
    const float* A    = (const float*)d_in[0];   // [B,N,N]
    const float* X    = (const float*)d_in[1];   // [B,N,D]
    const float* W    = (const float*)d_in[3];   // [D,1]
    const float* bias = (const float*)d_in[4];   // [1]

    float* out        = (float*)d_out;
    float* out_hidden = out;                                     // B*K*D
    float* out_gi     = out + (size_t)BGR * KKP * DFD;           // B*K (as float)
    float* out_adj    = out_gi + (size_t)BGR * KKP;              // B*K*K

    float* sup  = (float*)d_ws;                                  // B*N
    float* attn = sup + (size_t)BGR * NND;                       // B*N
    ull*   bm   = (ull*)(attn + (size_t)BGR * NND);              // B*N*8 ulls (4MB)
    uint*  bits = (uint*)(bm + (size_t)BGR * NND * 8);           // B*K*8 uints (1MB)
    float* dinv = (float*)(bits + (size_t)BGR * KKP * 8);        // B*K

    k_support<<<BGR * NND / 64, 256, 0, stream>>>(X, W, sup);
    k_score<<<BGR * 64, 256, 0, stream>>>(A, sup, bias, attn, bm);
    k_fuse<<<BGR, 512, 0, stream>>>(X, attn, (const uint*)bm, out_hidden, out_gi, bits, dinv);
    k_norm<<<BGR * 32, 256, 0, stream>>>(bits, dinv, out_adj);
}

// Round 3
// 70.526 us; speedup vs baseline: 1.1554x; 1.0068x over previous
//
#include <hip/hip_runtime.h>
#include <hip/hip_bf16.h>
#include <math.h>

#define BGR 128   // graphs
#define NND 512   // nodes per graph
#define DFD 128   // feature dim
#define KKP 256   // kept nodes per graph
#define HIDBLK 4096

typedef unsigned int uint;
typedef unsigned long long ull;

// ---------------- kernel 1: support[b][n] = dot(X[b][n], w) ----------------
__global__ __launch_bounds__(256) void k_support(const float* __restrict__ X,
                                                 const float* __restrict__ W,
                                                 float* __restrict__ sup) {
    __shared__ float w_s[DFD];
    int t = threadIdx.x;
    if (t < DFD) w_s[t] = W[t];
    __syncthreads();
    int node = blockIdx.x * 64 + (t >> 2);   // global node in [0, B*N)
    int q = t & 3;                            // quarter of the D=128 row
    const float4* xp = (const float4*)(X + (size_t)node * DFD + q * 32);
    const float4* wp = (const float4*)(w_s + q * 32);
    float sum = 0.f;
#pragma unroll
    for (int i = 0; i < 8; ++i) {
        float4 x = xp[i], w = wp[i];
        sum += x.x * w.x + x.y * w.y + x.z * w.z + x.w * w.w;
    }
    sum += __shfl_xor(sum, 1);
    sum += __shfl_xor(sum, 2);
    if (q == 0) sup[node] = sum;
}

// --- kernel 2: attn = tanh(A·sup + b); ALSO emit packed binarized bitmask of A ---
// bm layout per row: 8 ulls indexed k = h*4+c (h = col>>8, c = col&3);
// bit position within ull = (col>>2)&63.
__global__ __launch_bounds__(256) void k_score(const float* __restrict__ A,
                                               const float* __restrict__ sup,
                                               const float* __restrict__ bias,
                                               float* __restrict__ attn,
                                               ull* __restrict__ bm) {
    __shared__ float sup_s[NND];
    int b = blockIdx.x >> 6;       // 64 blocks per graph, 8 rows per block
    int rblk = blockIdx.x & 63;
    int t = threadIdx.x;
    sup_s[t] = sup[b * NND + t];
    sup_s[256 + t] = sup[b * NND + 256 + t];
    __syncthreads();
    int wave = t >> 6, l = t & 63;
    float bias0 = bias[0];
    const float4* sp = (const float4*)sup_s;
    float4 s0 = sp[l], s1 = sp[64 + l];
#pragma unroll
    for (int r = 0; r < 2; ++r) {
        int row = rblk * 8 + wave * 2 + r;
        const float4* ap = (const float4*)(A + ((size_t)b * NND + row) * NND);
        float4 a0 = ap[l], a1 = ap[64 + l];
        float sum = a0.x * s0.x + a0.y * s0.y + a0.z * s0.z + a0.w * s0.w
                  + a1.x * s1.x + a1.y * s1.y + a1.z * s1.z + a1.w * s1.w;
        int c0 = 4 * l;
        ull m[8];
        m[0] = __ballot(a0.x != 0.f && (c0 + 0) != row);
        m[1] = __ballot(a0.y != 0.f && (c0 + 1) != row);
        m[2] = __ballot(a0.z != 0.f && (c0 + 2) != row);
        m[3] = __ballot(a0.w != 0.f && (c0 + 3) != row);
        m[4] = __ballot(a1.x != 0.f && (256 + c0 + 0) != row);
        m[5] = __ballot(a1.y != 0.f && (256 + c0 + 1) != row);
        m[6] = __ballot(a1.z != 0.f && (256 + c0 + 2) != row);
        m[7] = __ballot(a1.w != 0.f && (256 + c0 + 3) != row);
#pragma unroll
        for (int off = 32; off >= 1; off >>= 1) sum += __shfl_down(sum, off);
        if (l == 0) {
            attn[b * NND + row] = tanhf(sum + bias0);
            ull* bp = bm + ((size_t)b * NND + row) * 8;
#pragma unroll
            for (int k = 0; k < 8; ++k) bp[k] = m[k];
        }
    }
}

// --- kernel 3: top-K ranks -> idx/gidx, indicator, K x K bits + dinv ---
__global__ __launch_bounds__(512) void k_fuse(const float* __restrict__ attn,
                                              const uint* __restrict__ bm,
                                              float* __restrict__ out_gi,
                                              int* __restrict__ gidx,
                                              uint* __restrict__ bits,
                                              float* __restrict__ dinv) {
    __shared__ float attn_s[NND];
    __shared__ uint km[16];              // keep bitmask over 512 nodes
    __shared__ int idx_s[KKP];
    __shared__ uint4 bm_s4[KKP][4];      // gathered bitmask rows (16 uints each)
    __shared__ uint bits_s[KKP][8];      // K x K packed bits, K-order
    int b = blockIdx.x, t = threadIdx.x;
    attn_s[t] = attn[b * NND + t];
    __syncthreads();
    int wave = t >> 6, l = t & 63;

    // rank of node t (strictly-greater, ties broken by smaller index)
    float a = attn_s[t];
    int r = 0;
    const float4* ap4 = (const float4*)attn_s;
    for (int jj = 0; jj < 128; ++jj) {
        float4 v = ap4[jj];
        int j0 = jj * 4;
        r += (v.x > a || (v.x == a && j0     < t)) ? 1 : 0;
        r += (v.y > a || (v.y == a && j0 + 1 < t)) ? 1 : 0;
        r += (v.z > a || (v.z == a && j0 + 2 < t)) ? 1 : 0;
        r += (v.w > a || (v.w == a && j0 + 3 < t)) ? 1 : 0;
    }
    bool keep = r < KKP;
    ull mk = __ballot(keep);
    if (l == 0) { km[wave * 2] = (uint)mk; km[wave * 2 + 1] = (uint)(mk >> 32); }
    __syncthreads();
    if (keep) {
        int w = t >> 5, pos = 0;
        for (int u = 0; u < w; ++u) pos += __popc(km[u]);
        pos += __popc(km[w] & ((1u << (t & 31)) - 1u));
        idx_s[pos] = t;
        gidx[b * KKP + pos] = t;
    }
    if (t < KKP) out_gi[b * KKP + t] = (float)b;
    __syncthreads();

    // gather bitmask rows of kept nodes into LDS (64B per row, L2-hot)
    {
        int i = t >> 1, half = t & 1;
        const uint4* src = (const uint4*)(bm + ((size_t)b * NND + idx_s[i]) * 16) + half * 2;
        bm_s4[i][half * 2]     = src[0];
        bm_s4[i][half * 2 + 1] = src[1];
    }
    __syncthreads();

    // assemble K x K bits: thread t handles kept-col j = t&255, rows ii+rowoff
    const uint* bmw = (const uint*)bm_s4;
    int j = t & 255;
    int jn = idx_s[j];
    int widx = ((jn >> 8) * 4 + (jn & 3)) * 2 + ((jn >> 7) & 1);
    int bitpos = (jn >> 2) & 31;
    int rowoff = t >> 8;          // 0 or 1 (which half-block)
    int wq = (t >> 6) & 3;        // quarter of j-range this wave covers
    for (int ii = 0; ii < KKP; ii += 2) {
        int row = ii + rowoff;
        uint kb = (bmw[row * 16 + widx] >> bitpos) & 1u;
        ull mb = __ballot(kb != 0u);
        if (l == 0) {
            bits_s[row][wq * 2]     = (uint)mb;
            bits_s[row][wq * 2 + 1] = (uint)(mb >> 32);
            uint* gp = bits + ((size_t)b * KKP + row) * 8 + wq * 2;
            gp[0] = (uint)mb;
            gp[1] = (uint)(mb >> 32);
        }
    }
    __syncthreads();
    if (t < KKP) {
        int s = 1;   // + I_K diagonal
#pragma unroll
        for (int k = 0; k < 8; ++k) s += __popc(bits_s[t][k]);
        dinv[b * KKP + t] = 1.0f / sqrtf((float)s);
    }
}

// --- kernel 4 (grid-split tail): hidden gather-scale + adjacency normalize ---
__global__ __launch_bounds__(256) void k_tail(const float* __restrict__ X,
                                              const float* __restrict__ attn,
                                              const int* __restrict__ gidx,
                                              const uint* __restrict__ bits,
                                              const float* __restrict__ dinv,
                                              float* __restrict__ out_hidden,
                                              float* __restrict__ out_adj) {
    __shared__ float dinv_s[KKP];
    int blk = blockIdx.x;
    int t = threadIdx.x, wave = t >> 6, l = t & 63;
    if (blk < HIDBLK) {
        // hidden: 8 kept rows per block, one row per wave-pass
        int r0 = blk * 8 + wave * 2;
#pragma unroll
        for (int rr = 0; rr < 2; ++rr) {
            int r = r0 + rr;                 // global kept-row in [0, B*K)
            int b = r >> 8;
            int node = gidx[r];
            float s = attn[b * NND + node];
            const float2* xp = (const float2*)(X + ((size_t)b * NND + node) * DFD);
            float2 v = xp[l];
            v.x *= s; v.y *= s;
            ((float2*)(out_hidden + (size_t)r * DFD))[l] = v;
        }
    } else {
        int nb = blk - HIDBLK;
        int b = nb >> 2, q = nb & 3;         // 4 blocks/graph, 64 rows each
        if (t < KKP) dinv_s[t] = dinv[b * KKP + t];
        __syncthreads();
        float4 dj = ((const float4*)dinv_s)[l];      // dinv for cols 4l..4l+3
        const float* djp = &dj.x;
        for (int rr = 0; rr < 16; ++rr) {
            int i = q * 64 + wave * 16 + rr;
            float di = dinv_s[i];
            const uint* bp = bits + ((size_t)b * KKP + i) * 8;
            uint word = bp[l >> 3];
            int j0 = l * 4;
            float4 v;
            float* pv = &v.x;
#pragma unroll
            for (int c = 0; c < 4; ++c) {
                int j = j0 + c;
                float ah = ((word >> (j & 31)) & 1u) ? 1.0f : 0.0f;
                if (j == i) ah += 1.0f;              // + I_K
                pv[c] = ah * di * djp[c];
            }
            ((float4*)(out_adj + ((size_t)b * KKP + i) * KKP))[l] = v;
        }
    }
}

extern "C" void kernel_launch(void* const* d_in, const int* in_sizes, int n_in,
                              void* d_out, int out_size, void* d_ws, size_t ws_size,
                              hipStream_t stream) {
    const float* A    = (const float*)d_in[0];   // [B,N,N]
    const float* X    = (const float*)d_in[1];   // [B,N,D]
    const float* W    = (const float*)d_in[3];   // [D,1]
    const float* bias = (const float*)d_in[4];   // [1]

    float* out        = (float*)d_out;
    float* out_hidden = out;                                     // B*K*D
    float* out_gi     = out + (size_t)BGR * KKP * DFD;           // B*K (as float)
    float* out_adj    = out_gi + (size_t)BGR * KKP;              // B*K*K

    float* sup  = (float*)d_ws;                                  // B*N
    float* attn = sup + (size_t)BGR * NND;                       // B*N
    ull*   bm   = (ull*)(attn + (size_t)BGR * NND);              // B*N*8 ulls (4MB)
    uint*  bits = (uint*)(bm + (size_t)BGR * NND * 8);           // B*K*8 uints (1MB)
    float* dinv = (float*)(bits + (size_t)BGR * KKP * 8);        // B*K
    int*   gidx = (int*)(dinv + (size_t)BGR * KKP);              // B*K

    k_support<<<BGR * NND / 64, 256, 0, stream>>>(X, W, sup);
    k_score<<<BGR * 64, 256, 0, stream>>>(A, sup, bias, attn, bm);
    k_fuse<<<BGR, 512, 0, stream>>>(attn, (const uint*)bm, out_gi, gidx, bits, dinv);
    k_tail<<<HIDBLK + BGR * 4, 256, 0, stream>>>(X, attn, gidx, bits, dinv,
                                                 out_hidden, out_adj);
}

// Round 4
// 70.322 us; speedup vs baseline: 1.1587x; 1.0029x over previous
//
#include <hip/hip_runtime.h>
#include <hip/hip_bf16.h>
#include <math.h>

#define BGR 128   // graphs
#define NND 512   // nodes per graph
#define DFD 128   // feature dim
#define KKP 256   // kept nodes per graph

typedef unsigned int uint;
typedef unsigned long long ull;

// ---------------- kernel 1: support[b][n] = dot(X[b][n], w) ----------------
__global__ __launch_bounds__(256) void k_support(const float* __restrict__ X,
                                                 const float* __restrict__ W,
                                                 float* __restrict__ sup) {
    __shared__ float w_s[DFD];
    int t = threadIdx.x;
    if (t < DFD) w_s[t] = W[t];
    __syncthreads();
    int node = blockIdx.x * 64 + (t >> 2);   // global node in [0, B*N)
    int q = t & 3;                            // quarter of the D=128 row
    const float4* xp = (const float4*)(X + (size_t)node * DFD + q * 32);
    const float4* wp = (const float4*)(w_s + q * 32);
    float sum = 0.f;
#pragma unroll
    for (int i = 0; i < 8; ++i) {
        float4 x = xp[i], w = wp[i];
        sum += x.x * w.x + x.y * w.y + x.z * w.z + x.w * w.w;
    }
    sum += __shfl_xor(sum, 1);
    sum += __shfl_xor(sum, 2);
    if (q == 0) sup[node] = sum;
}

// --- kernel 2: attn = tanh(A·sup + b); ALSO emit packed binarized bitmask of A ---
// bm layout per row: 8 ulls indexed k = h*4+c (h = col>>8, c = col&3);
// bit position within ull = (col>>2)&63.
__global__ __launch_bounds__(256) void k_score(const float* __restrict__ A,
                                               const float* __restrict__ sup,
                                               const float* __restrict__ bias,
                                               float* __restrict__ attn,
                                               ull* __restrict__ bm) {
    __shared__ float sup_s[NND];
    int b = blockIdx.x >> 6;       // 64 blocks per graph, 8 rows per block
    int rblk = blockIdx.x & 63;
    int t = threadIdx.x;
    sup_s[t] = sup[b * NND + t];
    sup_s[256 + t] = sup[b * NND + 256 + t];
    __syncthreads();
    int wave = t >> 6, l = t & 63;
    float bias0 = bias[0];
    const float4* sp = (const float4*)sup_s;
    float4 s0 = sp[l], s1 = sp[64 + l];
#pragma unroll
    for (int r = 0; r < 2; ++r) {
        int row = rblk * 8 + wave * 2 + r;
        const float4* ap = (const float4*)(A + ((size_t)b * NND + row) * NND);
        float4 a0 = ap[l], a1 = ap[64 + l];
        float sum = a0.x * s0.x + a0.y * s0.y + a0.z * s0.z + a0.w * s0.w
                  + a1.x * s1.x + a1.y * s1.y + a1.z * s1.z + a1.w * s1.w;
        int c0 = 4 * l;
        ull m[8];
        m[0] = __ballot(a0.x != 0.f && (c0 + 0) != row);
        m[1] = __ballot(a0.y != 0.f && (c0 + 1) != row);
        m[2] = __ballot(a0.z != 0.f && (c0 + 2) != row);
        m[3] = __ballot(a0.w != 0.f && (c0 + 3) != row);
        m[4] = __ballot(a1.x != 0.f && (256 + c0 + 0) != row);
        m[5] = __ballot(a1.y != 0.f && (256 + c0 + 1) != row);
        m[6] = __ballot(a1.z != 0.f && (256 + c0 + 2) != row);
        m[7] = __ballot(a1.w != 0.f && (256 + c0 + 3) != row);
#pragma unroll
        for (int off = 32; off >= 1; off >>= 1) sum += __shfl_down(sum, off);
        if (l == 0) {
            attn[b * NND + row] = tanhf(sum + bias0);
            ull* bp = bm + ((size_t)b * NND + row) * 8;
#pragma unroll
            for (int k = 0; k < 8; ++k) bp[k] = m[k];
        }
    }
}

// --- kernel 3 (mega): 4 blocks/graph. Each block: rank/top-K (duplicated, LDS-only),
// bm gather -> K x K bits -> dinv (all LDS), then writes its quarter of
// hidden rows and adjacency rows. No intermediate globals besides attn/bm.
__global__ __launch_bounds__(512) void k_mega(const float* __restrict__ X,
                                              const float* __restrict__ attn,
                                              const uint* __restrict__ bm,
                                              float* __restrict__ out_hidden,
                                              float* __restrict__ out_gi,
                                              float* __restrict__ out_adj) {
    __shared__ float attn_s[NND];
    __shared__ uint km[16];              // keep bitmask over 512 nodes
    __shared__ int idx_s[KKP];
    __shared__ uint4 bm_s4[KKP][4];      // gathered bitmask rows (16 uints each)
    __shared__ uint bits_s[KKP][8];      // K x K packed bits, K-order
    __shared__ float dinv_s[KKP];
    int b = blockIdx.x >> 2, q = blockIdx.x & 3;
    int t = threadIdx.x, wave = t >> 6, l = t & 63;
    attn_s[t] = attn[b * NND + t];
    __syncthreads();

    // rank of node t (strictly-greater, ties broken by smaller index)
    float a = attn_s[t];
    int r = 0;
    const float4* ap4 = (const float4*)attn_s;
    for (int jj = 0; jj < 128; ++jj) {
        float4 v = ap4[jj];
        int j0 = jj * 4;
        r += (v.x > a || (v.x == a && j0     < t)) ? 1 : 0;
        r += (v.y > a || (v.y == a && j0 + 1 < t)) ? 1 : 0;
        r += (v.z > a || (v.z == a && j0 + 2 < t)) ? 1 : 0;
        r += (v.w > a || (v.w == a && j0 + 3 < t)) ? 1 : 0;
    }
    bool keep = r < KKP;
    ull mk = __ballot(keep);
    if (l == 0) { km[wave * 2] = (uint)mk; km[wave * 2 + 1] = (uint)(mk >> 32); }
    __syncthreads();
    if (keep) {
        int w = t >> 5, pos = 0;
        for (int u = 0; u < w; ++u) pos += __popc(km[u]);
        pos += __popc(km[w] & ((1u << (t & 31)) - 1u));
        idx_s[pos] = t;
    }
    __syncthreads();

    // issue bm-row gather (latency hides under the hidden loop below)
    {
        int i = t >> 1, half = t & 1;
        const uint4* src = (const uint4*)(bm + ((size_t)b * NND + idx_s[i]) * 16) + half * 2;
        bm_s4[i][half * 2]     = src[0];
        bm_s4[i][half * 2 + 1] = src[1];
    }

    // hidden: this block's quarter (64 kept rows), one row per wave per iter
    if (t < KKP) out_gi[b * KKP + t] = (float)b;
#pragma unroll
    for (int it = 0; it < 8; ++it) {
        int k = q * 64 + it * 8 + wave;
        int node = idx_s[k];
        float s = attn_s[node];
        const float2* xp = (const float2*)(X + ((size_t)b * NND + node) * DFD);
        float2 v = xp[l];
        v.x *= s; v.y *= s;
        ((float2*)(out_hidden + ((size_t)b * KKP + k) * DFD))[l] = v;
    }
    __syncthreads();

    // assemble K x K bits: thread t handles kept-col j = t&255, rows ii+rowoff
    const uint* bmw = (const uint*)bm_s4;
    int jn = idx_s[t & 255];
    int widx = ((jn >> 8) * 4 + (jn & 3)) * 2 + ((jn >> 7) & 1);
    int bitpos = (jn >> 2) & 31;
    int rowoff = t >> 8;          // 0 or 1 (which half-block)
    int wq = (t >> 6) & 3;        // quarter of j-range this wave covers
    for (int ii = 0; ii < KKP; ii += 2) {
        int row = ii + rowoff;
        uint kb = (bmw[row * 16 + widx] >> bitpos) & 1u;
        ull mb = __ballot(kb != 0u);
        if (l == 0) {
            bits_s[row][wq * 2]     = (uint)mb;
            bits_s[row][wq * 2 + 1] = (uint)(mb >> 32);
        }
    }
    __syncthreads();
    if (t < KKP) {
        int s = 1;   // + I_K diagonal
#pragma unroll
        for (int k = 0; k < 8; ++k) s += __popc(bits_s[t][k]);
        dinv_s[t] = 1.0f / sqrtf((float)s);
    }
    __syncthreads();

    // adjacency: this block's quarter (64 rows), one row per wave per iter
    float4 dj = ((const float4*)dinv_s)[l];          // dinv for cols 4l..4l+3
    const float* djp = &dj.x;
#pragma unroll
    for (int it = 0; it < 8; ++it) {
        int i = q * 64 + it * 8 + wave;
        float di = dinv_s[i];
        uint word = bits_s[i][l >> 3];
        int j0 = l * 4;
        float4 v;
        float* pv = &v.x;
#pragma unroll
        for (int c = 0; c < 4; ++c) {
            int j = j0 + c;
            float ah = ((word >> (j & 31)) & 1u) ? 1.0f : 0.0f;
            if (j == i) ah += 1.0f;                  // + I_K
            pv[c] = ah * di * djp[c];
        }
        ((float4*)(out_adj + ((size_t)b * KKP + i) * KKP))[l] = v;
    }
}

extern "C" void kernel_launch(void* const* d_in, const int* in_sizes, int n_in,
                              void* d_out, int out_size, void* d_ws, size_t ws_size,
                              hipStream_t stream) {
    const float* A    = (const float*)d_in[0];   // [B,N,N]
    const float* X    = (const float*)d_in[1];   // [B,N,D]
    const float* W    = (const float*)d_in[3];   // [D,1]
    const float* bias = (const float*)d_in[4];   // [1]

    float* out        = (float*)d_out;
    float* out_hidden = out;                                     // B*K*D
    float* out_gi     = out + (size_t)BGR * KKP * DFD;           // B*K (as float)
    float* out_adj    = out_gi + (size_t)BGR * KKP;              // B*K*K

    float* sup  = (float*)d_ws;                                  // B*N
    float* attn = sup + (size_t)BGR * NND;                       // B*N
    ull*   bm   = (ull*)(attn + (size_t)BGR * NND);              // B*N*8 ulls (4MB)

    k_support<<<BGR * NND / 64, 256, 0, stream>>>(X, W, sup);
    k_score<<<BGR * 64, 256, 0, stream>>>(A, sup, bias, attn, bm);
    k_mega<<<BGR * 4, 512, 0, stream>>>(X, attn, (const uint*)bm,
                                        out_hidden, out_gi, out_adj);
}